// Round 1
// baseline (587.415 us; speedup 1.0000x reference)
//
#include <hip/hip_runtime.h>

#define IN_F 8192
#define OUT_F 8192
#define THRESHOLD_F 50.0f
#define TARGET_RATE 0.1f

// One block per output row. 256 threads, each handles 32 elements (8 x float4).
// Phase A: stage clipped x into LDS. Phase B: ternary-weight dot product over
// the S row -> spike/v_mem/threshold. Phase C: stream E row -> new_trace row.
// Memory-bound: ~768 MB HBM traffic (S read + E read + trace write).
__global__ __launch_bounds__(256, 4) void snn_fused_kernel(
    const float* __restrict__ spike_input,        // [IN_F]
    const float* __restrict__ synapse_states,     // [OUT_F, IN_F]
    const float* __restrict__ membrane_potential, // [OUT_F]
    const float* __restrict__ adaptive_threshold, // [OUT_F]
    const float* __restrict__ eligibility_trace,  // [OUT_F, IN_F]
    float* __restrict__ out_spikes,               // [OUT_F]
    float* __restrict__ out_vmem,                 // [OUT_F]
    float* __restrict__ out_thresh,               // [OUT_F]
    float* __restrict__ out_trace)                // [OUT_F, IN_F]
{
    __shared__ float xs[IN_F];      // 32 KB: clipped input x
    __shared__ float wave_sum[4];
    __shared__ float s_spike;

    const int o   = blockIdx.x;
    const int tid = threadIdx.x;

    // ---- Phase A: stage x = clip(spike_input*2, 0, 1) into LDS ----
    const float4* x4 = (const float4*)spike_input;
    float4* xs4 = (float4*)xs;
    #pragma unroll
    for (int k = 0; k < 8; ++k) {
        int idx = tid + k * 256;            // float4 index in [0, 2048)
        float4 v = x4[idx];
        v.x = fminf(fmaxf(v.x * 2.0f, 0.0f), 1.0f);
        v.y = fminf(fmaxf(v.y * 2.0f, 0.0f), 1.0f);
        v.z = fminf(fmaxf(v.z * 2.0f, 0.0f), 1.0f);
        v.w = fminf(fmaxf(v.w * 2.0f, 0.0f), 1.0f);
        xs4[idx] = v;
    }
    __syncthreads();

    // ---- Phase B: current = sum_i (S[o,i] > 50) * x[i] ----
    const float4* s4 = (const float4*)(synapse_states + (size_t)o * IN_F);
    float sum = 0.0f;
    #pragma unroll
    for (int k = 0; k < 8; ++k) {
        int idx = tid + k * 256;
        float4 s = s4[idx];
        float4 v = xs4[idx];
        sum += (s.x > THRESHOLD_F ? v.x : 0.0f)
             + (s.y > THRESHOLD_F ? v.y : 0.0f)
             + (s.z > THRESHOLD_F ? v.z : 0.0f)
             + (s.w > THRESHOLD_F ? v.w : 0.0f);
    }
    // wave (64-lane) reduction
    #pragma unroll
    for (int off = 32; off > 0; off >>= 1)
        sum += __shfl_down(sum, off, 64);
    if ((tid & 63) == 0) wave_sum[tid >> 6] = sum;
    __syncthreads();

    if (tid == 0) {
        float current = wave_sum[0] + wave_sum[1] + wave_sum[2] + wave_sum[3];
        float v_mem = membrane_potential[o] * 0.7f + current;
        float thr   = adaptive_threshold[o];
        float spike = (v_mem >= thr) ? 1.0f : 0.0f;
        out_spikes[o] = spike;
        out_vmem[o]   = v_mem * (1.0f - spike) * 0.3f;
        out_thresh[o] = fminf(fmaxf(thr + (spike - TARGET_RATE) * 0.05f, 0.5f), 5.0f);
        s_spike = spike;
    }
    __syncthreads();
    const float spike = s_spike;

    // ---- Phase C: new_trace[o,i] = clip(E[o,i]*0.8 + spike*x[i], 0, 3) ----
    const float4* e4 = (const float4*)(eligibility_trace + (size_t)o * IN_F);
    float4* t4 = (float4*)(out_trace + (size_t)o * IN_F);
    #pragma unroll
    for (int k = 0; k < 8; ++k) {
        int idx = tid + k * 256;
        float4 e = e4[idx];
        float4 v = xs4[idx];
        float4 t;
        t.x = fminf(fmaxf(e.x * 0.8f + spike * v.x, 0.0f), 3.0f);
        t.y = fminf(fmaxf(e.y * 0.8f + spike * v.y, 0.0f), 3.0f);
        t.z = fminf(fmaxf(e.z * 0.8f + spike * v.z, 0.0f), 3.0f);
        t.w = fminf(fmaxf(e.w * 0.8f + spike * v.w, 0.0f), 3.0f);
        t4[idx] = t;
    }
}

extern "C" void kernel_launch(void* const* d_in, const int* in_sizes, int n_in,
                              void* d_out, int out_size, void* d_ws, size_t ws_size,
                              hipStream_t stream) {
    const float* spike_input        = (const float*)d_in[0];
    const float* synapse_states     = (const float*)d_in[1];
    const float* membrane_potential = (const float*)d_in[2];
    const float* adaptive_threshold = (const float*)d_in[3];
    const float* eligibility_trace  = (const float*)d_in[4];

    float* out = (float*)d_out;
    float* out_spikes = out;                         // [OUT_F]
    float* out_vmem   = out + OUT_F;                 // [OUT_F]
    float* out_thresh = out + 2 * OUT_F;             // [OUT_F]
    float* out_trace  = out + 3 * OUT_F;             // [OUT_F, IN_F]

    snn_fused_kernel<<<OUT_F, 256, 0, stream>>>(
        spike_input, synapse_states, membrane_potential, adaptive_threshold,
        eligibility_trace, out_spikes, out_vmem, out_thresh, out_trace);
}

// Round 2
// 582.321 us; speedup vs baseline: 1.0087x; 1.0087x over previous
//
#include <hip/hip_runtime.h>

#define IN_F 8192
#define OUT_F 8192
#define THRESHOLD_F 50.0f
#define TARGET_RATE 0.1f

// ---------------- K1: per-row ternary dot product + neuron update ----------
// One block (256 threads) per output row. Reads S row (coalesced float4) and
// x directly from global (32 KB, L2-resident after first touch). No LDS tile,
// no phase barriers except the single cross-wave combine.
__global__ __launch_bounds__(256) void snn_reduce_kernel(
    const float* __restrict__ spike_input,        // [IN_F]
    const float* __restrict__ synapse_states,     // [OUT_F, IN_F]
    const float* __restrict__ membrane_potential, // [OUT_F]
    const float* __restrict__ adaptive_threshold, // [OUT_F]
    float* __restrict__ out_spikes,               // [OUT_F]
    float* __restrict__ out_vmem,                 // [OUT_F]
    float* __restrict__ out_thresh)               // [OUT_F]
{
    __shared__ float wave_sum[4];

    const int o   = blockIdx.x;
    const int tid = threadIdx.x;

    const float4* s4 = (const float4*)(synapse_states + (size_t)o * IN_F);
    const float4* x4 = (const float4*)spike_input;

    float sum = 0.0f;
    #pragma unroll
    for (int k = 0; k < 8; ++k) {
        int idx = tid + k * 256;               // float4 index in [0, 2048)
        float4 s = s4[idx];
        float4 v = x4[idx];
        v.x = fminf(fmaxf(v.x * 2.0f, 0.0f), 1.0f);
        v.y = fminf(fmaxf(v.y * 2.0f, 0.0f), 1.0f);
        v.z = fminf(fmaxf(v.z * 2.0f, 0.0f), 1.0f);
        v.w = fminf(fmaxf(v.w * 2.0f, 0.0f), 1.0f);
        sum += (s.x > THRESHOLD_F ? v.x : 0.0f)
             + (s.y > THRESHOLD_F ? v.y : 0.0f)
             + (s.z > THRESHOLD_F ? v.z : 0.0f)
             + (s.w > THRESHOLD_F ? v.w : 0.0f);
    }
    // 64-lane wave reduction
    #pragma unroll
    for (int off = 32; off > 0; off >>= 1)
        sum += __shfl_down(sum, off, 64);
    if ((tid & 63) == 0) wave_sum[tid >> 6] = sum;
    __syncthreads();

    if (tid == 0) {
        float current = wave_sum[0] + wave_sum[1] + wave_sum[2] + wave_sum[3];
        float v_mem = membrane_potential[o] * 0.7f + current;
        float thr   = adaptive_threshold[o];
        float spike = (v_mem >= thr) ? 1.0f : 0.0f;
        out_spikes[o] = spike;
        out_vmem[o]   = v_mem * (1.0f - spike) * 0.3f;
        out_thresh[o] = fminf(fmaxf(thr + (spike - TARGET_RATE) * 0.05f, 0.5f), 5.0f);
    }
}

// ---------------- K2: pure streaming trace update ---------------------------
// Grid-stride over 16M float4 elements. new_trace = clip(E*0.8 + spike*x, 0, 3).
// spike[row] and x[i] are L2-resident (32 KB each); E read + T write is the
// 512 MB HBM stream. No barriers, minimal registers -> max occupancy.
__global__ __launch_bounds__(256) void snn_trace_kernel(
    const float* __restrict__ spike_input,        // [IN_F]
    const float* __restrict__ eligibility_trace,  // [OUT_F, IN_F]
    const float* __restrict__ out_spikes,         // [OUT_F]
    float* __restrict__ out_trace)                // [OUT_F, IN_F]
{
    const int total4 = (OUT_F * IN_F) / 4;        // 16,777,216 float4s
    const int nthreads = gridDim.x * blockDim.x;
    const float4* e4 = (const float4*)eligibility_trace;
    const float4* x4 = (const float4*)spike_input;
    float4* t4 = (float4*)out_trace;

    for (int idx = blockIdx.x * blockDim.x + threadIdx.x; idx < total4; idx += nthreads) {
        int row = idx >> 11;                      // 2048 float4s per row
        int col = idx & 2047;
        float  spike = out_spikes[row];
        float4 e = e4[idx];
        float4 v = x4[col];
        float4 t;
        t.x = fminf(fmaxf(e.x * 0.8f + spike * fminf(fmaxf(v.x * 2.0f, 0.0f), 1.0f), 0.0f), 3.0f);
        t.y = fminf(fmaxf(e.y * 0.8f + spike * fminf(fmaxf(v.y * 2.0f, 0.0f), 1.0f), 0.0f), 3.0f);
        t.z = fminf(fmaxf(e.z * 0.8f + spike * fminf(fmaxf(v.z * 2.0f, 0.0f), 1.0f), 0.0f), 3.0f);
        t.w = fminf(fmaxf(e.w * 0.8f + spike * fminf(fmaxf(v.w * 2.0f, 0.0f), 1.0f), 0.0f), 3.0f);
        t4[idx] = t;
    }
}

extern "C" void kernel_launch(void* const* d_in, const int* in_sizes, int n_in,
                              void* d_out, int out_size, void* d_ws, size_t ws_size,
                              hipStream_t stream) {
    const float* spike_input        = (const float*)d_in[0];
    const float* synapse_states     = (const float*)d_in[1];
    const float* membrane_potential = (const float*)d_in[2];
    const float* adaptive_threshold = (const float*)d_in[3];
    const float* eligibility_trace  = (const float*)d_in[4];

    float* out = (float*)d_out;
    float* out_spikes = out;                      // [OUT_F]
    float* out_vmem   = out + OUT_F;              // [OUT_F]
    float* out_thresh = out + 2 * OUT_F;          // [OUT_F]
    float* out_trace  = out + 3 * OUT_F;          // [OUT_F, IN_F]

    snn_reduce_kernel<<<OUT_F, 256, 0, stream>>>(
        spike_input, synapse_states, membrane_potential, adaptive_threshold,
        out_spikes, out_vmem, out_thresh);

    // 8 float4s per thread: 16M / (8192*256) = 8 grid-stride iterations.
    snn_trace_kernel<<<8192, 256, 0, stream>>>(
        spike_input, eligibility_trace, out_spikes, out_trace);
}

// Round 4
// 579.276 us; speedup vs baseline: 1.0141x; 1.0053x over previous
//
#include <hip/hip_runtime.h>

#define IN_F 8192
#define OUT_F 8192
#define THRESHOLD_F 50.0f
#define TARGET_RATE 0.1f

// clang-native vector type: required by __builtin_nontemporal_load/store
typedef float f32x4 __attribute__((ext_vector_type(4)));

// One WAVE per output row; 4 waves (4 rows) per 256-thread block; no LDS, no
// barriers. Each wave: reduce S row -> butterfly shuffle (all lanes get sum)
// -> spike -> stream E row -> trace row. Waves pipeline independently so the
// memory system never drains at a phase boundary.
__global__ __launch_bounds__(256) void snn_wave_fused(
    const float* __restrict__ spike_input,        // [IN_F]
    const float* __restrict__ synapse_states,     // [OUT_F, IN_F]
    const float* __restrict__ membrane_potential, // [OUT_F]
    const float* __restrict__ adaptive_threshold, // [OUT_F]
    const float* __restrict__ eligibility_trace,  // [OUT_F, IN_F]
    float* __restrict__ out_spikes,               // [OUT_F]
    float* __restrict__ out_vmem,                 // [OUT_F]
    float* __restrict__ out_thresh,               // [OUT_F]
    float* __restrict__ out_trace)                // [OUT_F, IN_F]
{
    const int row  = (blockIdx.x << 2) + (threadIdx.x >> 6);  // wave id = row
    const int lane = threadIdx.x & 63;

    const f32x4* x4 = (const f32x4*)spike_input;
    const f32x4* s4 = (const f32x4*)(synapse_states + (size_t)row * IN_F);

    // ---- Phase 1: current = sum_i (S[row,i] > 50) * clip(2*x[i],0,1) ----
    float sum = 0.0f;
    #pragma unroll 8
    for (int k = 0; k < 32; ++k) {
        int idx = lane + (k << 6);                 // f32x4 idx in [0, 2048)
        f32x4 s = __builtin_nontemporal_load(&s4[idx]);  // single-use: don't cache
        f32x4 v = x4[idx];                               // hot in L1/L2
        v.x = fminf(fmaxf(v.x * 2.0f, 0.0f), 1.0f);
        v.y = fminf(fmaxf(v.y * 2.0f, 0.0f), 1.0f);
        v.z = fminf(fmaxf(v.z * 2.0f, 0.0f), 1.0f);
        v.w = fminf(fmaxf(v.w * 2.0f, 0.0f), 1.0f);
        sum += (s.x > THRESHOLD_F ? v.x : 0.0f)
             + (s.y > THRESHOLD_F ? v.y : 0.0f)
             + (s.z > THRESHOLD_F ? v.z : 0.0f)
             + (s.w > THRESHOLD_F ? v.w : 0.0f);
    }
    // Butterfly reduction: every lane ends with the identical full sum
    #pragma unroll
    for (int m = 1; m < 64; m <<= 1)
        sum += __shfl_xor(sum, m, 64);

    // ---- Phase 2: neuron update (all lanes compute; lane 0 writes) ----
    float v_mem = membrane_potential[row] * 0.7f + sum;   // wave-broadcast load
    float thr   = adaptive_threshold[row];
    float spike = (v_mem >= thr) ? 1.0f : 0.0f;
    if (lane == 0) {
        out_spikes[row] = spike;
        out_vmem[row]   = v_mem * (1.0f - spike) * 0.3f;
        out_thresh[row] = fminf(fmaxf(thr + (spike - TARGET_RATE) * 0.05f, 0.5f), 5.0f);
    }

    // ---- Phase 3: new_trace[row,i] = clip(E*0.8 + spike*x, 0, 3) ----
    const f32x4* e4 = (const f32x4*)(eligibility_trace + (size_t)row * IN_F);
    f32x4* t4 = (f32x4*)(out_trace + (size_t)row * IN_F);
    #pragma unroll 8
    for (int k = 0; k < 32; ++k) {
        int idx = lane + (k << 6);
        f32x4 e = __builtin_nontemporal_load(&e4[idx]);
        f32x4 v = x4[idx];
        f32x4 t;
        t.x = fminf(fmaxf(e.x * 0.8f + spike * fminf(fmaxf(v.x * 2.0f, 0.0f), 1.0f), 0.0f), 3.0f);
        t.y = fminf(fmaxf(e.y * 0.8f + spike * fminf(fmaxf(v.y * 2.0f, 0.0f), 1.0f), 0.0f), 3.0f);
        t.z = fminf(fmaxf(e.z * 0.8f + spike * fminf(fmaxf(v.z * 2.0f, 0.0f), 1.0f), 0.0f), 3.0f);
        t.w = fminf(fmaxf(e.w * 0.8f + spike * fminf(fmaxf(v.w * 2.0f, 0.0f), 1.0f), 0.0f), 3.0f);
        __builtin_nontemporal_store(t, &t4[idx]);   // streamed out, never re-read
    }
}

extern "C" void kernel_launch(void* const* d_in, const int* in_sizes, int n_in,
                              void* d_out, int out_size, void* d_ws, size_t ws_size,
                              hipStream_t stream) {
    const float* spike_input        = (const float*)d_in[0];
    const float* synapse_states     = (const float*)d_in[1];
    const float* membrane_potential = (const float*)d_in[2];
    const float* adaptive_threshold = (const float*)d_in[3];
    const float* eligibility_trace  = (const float*)d_in[4];

    float* out = (float*)d_out;
    float* out_spikes = out;                      // [OUT_F]
    float* out_vmem   = out + OUT_F;              // [OUT_F]
    float* out_thresh = out + 2 * OUT_F;          // [OUT_F]
    float* out_trace  = out + 3 * OUT_F;          // [OUT_F, IN_F]

    // 4 rows (waves) per block -> 2048 blocks.
    snn_wave_fused<<<OUT_F / 4, 256, 0, stream>>>(
        spike_input, synapse_states, membrane_potential, adaptive_threshold,
        eligibility_trace, out_spikes, out_vmem, out_thresh, out_trace);
}